// Round 1
// baseline (1303.677 us; speedup 1.0000x reference)
//
#include <hip/hip_runtime.h>
#include <stdint.h>

typedef unsigned short u16;
typedef __attribute__((ext_vector_type(8))) short short8;
typedef __attribute__((ext_vector_type(4))) float f32x4;

#define NCTX 4096
#define NTGT 2048
#define DMODEL 1024
#define NH 16
#define HD 64

__device__ inline u16 f2b(float f) {
  union { float f; uint32_t u; } x; x.f = f;
  uint32_t u = x.u;
  return (u16)((u + 0x7fffu + ((u >> 16) & 1u)) >> 16);
}

// ---------------- f32 -> bf16 conversion ----------------
__global__ void cvt_bf16(const float* __restrict__ in, u16* __restrict__ out, int n4) {
  int i = blockIdx.x * blockDim.x + threadIdx.x;
  if (i >= n4) return;
  const float4 v = ((const float4*)in)[i];
  uint32_t lo = (uint32_t)f2b(v.x) | ((uint32_t)f2b(v.y) << 16);
  uint32_t hi = (uint32_t)f2b(v.z) | ((uint32_t)f2b(v.w) << 16);
  ((uint2*)out)[i] = make_uint2(lo, hi);
}

// ---------------- generic C = A * B^T  (bf16 in, f32 accum) ----------------
// A: [M][Kd] bf16 row-major; B: [N][Kd] bf16 row-major.
// MODE 0: write f32 C[M][N] to Cf.
// MODE 1: K-writer: N column n maps to (h = n>>6, z = n&63);
//         writes Ck[h][k][z] and Ckt[h][z][k] (both bf16), M must be NCTX.
template<int MODE>
__global__ __launch_bounds__(256) void gemm_bt(
    const u16* __restrict__ A, const u16* __restrict__ B,
    float* __restrict__ Cf, u16* __restrict__ Ck, u16* __restrict__ Ckt,
    int M, int N, int Kd) {
  const int bm = blockIdx.x % (M >> 6);
  const int bn = blockIdx.x / (M >> 6);
  const int w = threadIdx.x >> 6, l = threadIdx.x & 63;
  const int lg = l >> 4, lm = l & 15;
  const int m0 = (bm << 6) + (w << 4);
  const int n0 = bn << 6;

  const u16* Ar = A + (size_t)(m0 + lm) * Kd;
  f32x4 acc[4] = {};

  for (int kd = 0; kd < Kd; kd += 64) {
    short8 a0 = *(const short8*)(Ar + kd + lg * 8);
    short8 a1 = *(const short8*)(Ar + kd + 32 + lg * 8);
#pragma unroll
    for (int nf = 0; nf < 4; ++nf) {
      const u16* Br = B + (size_t)(n0 + nf * 16 + lm) * Kd + kd + lg * 8;
      short8 b0 = *(const short8*)(Br);
      short8 b1 = *(const short8*)(Br + 32);
      acc[nf] = __builtin_amdgcn_mfma_f32_16x16x32_bf16(a0, b0, acc[nf], 0, 0, 0);
      acc[nf] = __builtin_amdgcn_mfma_f32_16x16x32_bf16(a1, b1, acc[nf], 0, 0, 0);
    }
  }

  if (MODE == 0) {
#pragma unroll
    for (int nf = 0; nf < 4; ++nf)
#pragma unroll
      for (int r = 0; r < 4; ++r)
        Cf[(size_t)(m0 + lg * 4 + r) * N + (n0 + nf * 16 + lm)] = acc[nf][r];
  } else {
#pragma unroll
    for (int nf = 0; nf < 4; ++nf) {
      int n = n0 + nf * 16 + lm;
      int h = n >> 6, z = n & 63;
#pragma unroll
      for (int r = 0; r < 4; ++r) {
        int k = m0 + lg * 4 + r;
        u16 b = f2b(acc[nf][r]);
        Ck[((size_t)h * NCTX + k) * HD + z] = b;
        Ckt[((size_t)h * HD + z) * NCTX + k] = b;
      }
    }
  }
}

// ---------------- 5-step energy attention ----------------
// grid: 512 blocks (16 heads x 32 q-tiles of 64), 256 threads (4 waves).
// wave w owns 16 q rows; waves fully independent (no __syncthreads).
__global__ __launch_bounds__(256) void attn5(
    const u16* __restrict__ Kbf,   // [NH][NCTX][HD]
    const u16* __restrict__ Ktb,   // [NH][HD][NCTX]
    const float* __restrict__ Qf,  // [NTGT][DMODEL]  col = h*64+z
    u16* __restrict__ Qob) {       // [NTGT][DMODEL] bf16 out
  __shared__ u16 lds[4][1024];     // per-wave 16x64 staging, XOR-swizzled

  const int bid = blockIdx.x;
  const int h  = ((bid & 7) << 1) | ((bid >> 3) & 1);  // XCD-friendly head map
  const int qt = bid >> 4;
  const int w = threadIdx.x >> 6, l = threadIdx.x & 63;
  const int lg = l >> 4, lm = l & 15;
  const int q0 = qt * 64 + w * 16;

  const u16* Kh  = Kbf + (size_t)h * NCTX * HD;
  const u16* Kth = Ktb + (size_t)h * HD * NCTX;
  u16* my = lds[w];

  const float BL2E = 0.125f * 1.44269504088896340736f;  // beta * log2(e)

  // q in f32 registers, MFMA C-layout: qv[nf][r] = q[row=lg*4+r][z=nf*16+lm]
  float qv[4][4];
#pragma unroll
  for (int nf = 0; nf < 4; ++nf)
#pragma unroll
    for (int r = 0; r < 4; ++r)
      qv[nf][r] = Qf[(size_t)(q0 + lg * 4 + r) * DMODEL + h * HD + nf * 16 + lm];

  for (int step = 0; step < 5; ++step) {
    // stage q -> LDS (bf16) and load A-fragments
#pragma unroll
    for (int nf = 0; nf < 4; ++nf)
#pragma unroll
      for (int r = 0; r < 4; ++r) {
        int row = lg * 4 + r;
        my[(row << 6) + ((nf * 16 + lm) ^ ((row & 7) << 3))] = f2b(qv[nf][r]);
      }
    short8 qa0 = *(const short8*)&my[(lm << 6) + ((lg * 8) ^ ((lm & 7) << 3))];
    short8 qa1 = *(const short8*)&my[(lm << 6) + ((32 + lg * 8) ^ ((lm & 7) << 3))];

    float mrow[4] = {-1e30f, -1e30f, -1e30f, -1e30f};
    float lrow[4] = {0.f, 0.f, 0.f, 0.f};
    f32x4 ov[4] = {};

    for (int k0 = 0; k0 < NCTX; k0 += 64) {
      // ---- S = q K^T for this 16x64 tile ----
      f32x4 s[4] = {};
#pragma unroll
      for (int nf = 0; nf < 4; ++nf) {
        const u16* kp = Kh + (size_t)(k0 + nf * 16 + lm) * HD + lg * 8;
        short8 b0 = *(const short8*)kp;
        short8 b1 = *(const short8*)(kp + 32);
        s[nf] = __builtin_amdgcn_mfma_f32_16x16x32_bf16(qa0, b0, s[nf], 0, 0, 0);
        s[nf] = __builtin_amdgcn_mfma_f32_16x16x32_bf16(qa1, b1, s[nf], 0, 0, 0);
      }
      // ---- online softmax (exp2 domain) ----
      float p[4][4]; float sc[4];
#pragma unroll
      for (int r = 0; r < 4; ++r) {
        float t = fmaxf(fmaxf(s[0][r], s[1][r]), fmaxf(s[2][r], s[3][r]));
        t = fmaxf(t, __shfl_xor(t, 1));
        t = fmaxf(t, __shfl_xor(t, 2));
        t = fmaxf(t, __shfl_xor(t, 4));
        t = fmaxf(t, __shfl_xor(t, 8));
        t *= BL2E;
        float mn = fmaxf(mrow[r], t);
        sc[r] = exp2f(mrow[r] - mn);
        float ps = 0.f;
#pragma unroll
        for (int nf = 0; nf < 4; ++nf) {
          float pv = exp2f(fmaf(s[nf][r], BL2E, -mn));
          p[nf][r] = pv;
          ps += pv;
        }
        ps += __shfl_xor(ps, 1);
        ps += __shfl_xor(ps, 2);
        ps += __shfl_xor(ps, 4);
        ps += __shfl_xor(ps, 8);
        mrow[r] = mn;
        lrow[r] = lrow[r] * sc[r] + ps;
      }
#pragma unroll
      for (int nf = 0; nf < 4; ++nf)
#pragma unroll
        for (int r = 0; r < 4; ++r) ov[nf][r] *= sc[r];

      // ---- stage P (bf16) and do O += P * K ----
#pragma unroll
      for (int nf = 0; nf < 4; ++nf)
#pragma unroll
        for (int r = 0; r < 4; ++r) {
          int row = lg * 4 + r;
          my[(row << 6) + ((nf * 16 + lm) ^ ((row & 7) << 3))] = f2b(p[nf][r]);
        }
      short8 pa0 = *(const short8*)&my[(lm << 6) + ((lg * 8) ^ ((lm & 7) << 3))];
      short8 pa1 = *(const short8*)&my[(lm << 6) + ((32 + lg * 8) ^ ((lm & 7) << 3))];
#pragma unroll
      for (int nf = 0; nf < 4; ++nf) {
        const u16* ktp = Kth + (size_t)(nf * 16 + lm) * NCTX + k0 + lg * 8;
        short8 c0 = *(const short8*)ktp;
        short8 c1 = *(const short8*)(ktp + 32);
        ov[nf] = __builtin_amdgcn_mfma_f32_16x16x32_bf16(pa0, c0, ov[nf], 0, 0, 0);
        ov[nf] = __builtin_amdgcn_mfma_f32_16x16x32_bf16(pa1, c1, ov[nf], 0, 0, 0);
      }
    }
    // ---- q += 0.1 * (P@K)/l ----
#pragma unroll
    for (int r = 0; r < 4; ++r) {
      float rl = 0.1f / lrow[r];
#pragma unroll
      for (int nf = 0; nf < 4; ++nf) qv[nf][r] += ov[nf][r] * rl;
    }
  }

  // write Q_opt as bf16 [NTGT][DMODEL]
#pragma unroll
  for (int nf = 0; nf < 4; ++nf)
#pragma unroll
    for (int r = 0; r < 4; ++r)
      Qob[(size_t)(q0 + lg * 4 + r) * DMODEL + h * HD + nf * 16 + lm] = f2b(qv[nf][r]);
}

extern "C" void kernel_launch(void* const* d_in, const int* in_sizes, int n_in,
                              void* d_out, int out_size, void* d_ws, size_t ws_size,
                              hipStream_t stream) {
  const float* ctx = (const float*)d_in[0];
  const float* tgt = (const float*)d_in[1];
  const float* Wq  = (const float*)d_in[2];
  const float* Wk  = (const float*)d_in[3];
  const float* Wo  = (const float*)d_in[4];

  uint8_t* wp = (uint8_t*)d_ws;
  u16* ctxb = (u16*)wp; wp += (size_t)NCTX * DMODEL * 2;
  u16* tgtb = (u16*)wp; wp += (size_t)NTGT * DMODEL * 2;
  u16* wqb  = (u16*)wp; wp += (size_t)DMODEL * DMODEL * 2;
  u16* wkb  = (u16*)wp; wp += (size_t)DMODEL * DMODEL * 2;
  u16* wob  = (u16*)wp; wp += (size_t)DMODEL * DMODEL * 2;
  u16* Kbf  = (u16*)wp; wp += (size_t)NH * NCTX * HD * 2;
  u16* Ktb  = (u16*)wp; wp += (size_t)NH * HD * NCTX * 2;
  float* Qf = (float*)wp; wp += (size_t)NTGT * DMODEL * 4;
  u16* Qob  = (u16*)wp; wp += (size_t)NTGT * DMODEL * 2;

  auto cvt = [&](const float* in, u16* out, size_t n) {
    int n4 = (int)(n / 4);
    hipLaunchKernelGGL(cvt_bf16, dim3((n4 + 255) / 256), dim3(256), 0, stream, in, out, n4);
  };
  cvt(ctx, ctxb, (size_t)NCTX * DMODEL);
  cvt(tgt, tgtb, (size_t)NTGT * DMODEL);
  cvt(Wq, wqb, (size_t)DMODEL * DMODEL);
  cvt(Wk, wkb, (size_t)DMODEL * DMODEL);
  cvt(Wo, wob, (size_t)DMODEL * DMODEL);

  // K projection: [NCTX,DMODEL] @ Wk^T -> K[h][k][z] and Kt[h][z][k]
  hipLaunchKernelGGL(gemm_bt<1>, dim3((NCTX / 64) * (DMODEL / 64)), dim3(256), 0, stream,
                     ctxb, wkb, (float*)nullptr, Kbf, Ktb, NCTX, DMODEL, DMODEL);
  // Q projection: [NTGT,DMODEL] @ Wq^T -> Qf (f32)
  hipLaunchKernelGGL(gemm_bt<0>, dim3((NTGT / 64) * (DMODEL / 64)), dim3(256), 0, stream,
                     tgtb, wqb, Qf, (u16*)nullptr, (u16*)nullptr, NTGT, DMODEL, DMODEL);
  // 5-step energy attention
  hipLaunchKernelGGL(attn5, dim3(512), dim3(256), 0, stream, Kbf, Ktb, Qf, Qob);
  // Output projection: Q_opt @ Wo^T -> d_out (f32)
  hipLaunchKernelGGL(gemm_bt<0>, dim3((NTGT / 64) * (DMODEL / 64)), dim3(256), 0, stream,
                     Qob, wob, (float*)d_out, (u16*)nullptr, (u16*)nullptr, NTGT, DMODEL, DMODEL);
}

// Round 2
// 1287.961 us; speedup vs baseline: 1.0122x; 1.0122x over previous
//
#include <hip/hip_runtime.h>
#include <stdint.h>

typedef unsigned short u16;
typedef __attribute__((ext_vector_type(8))) short short8;
typedef __attribute__((ext_vector_type(4))) float f32x4;

#define NCTX 4096
#define NTGT 2048
#define DMODEL 1024
#define NH 16
#define HD 64

__device__ inline u16 f2b(float f) {
  union { float f; uint32_t u; } x; x.f = f;
  uint32_t u = x.u;
  return (u16)((u + 0x7fffu + ((u >> 16) & 1u)) >> 16);
}

// ---------------- f32 -> bf16 conversion ----------------
__global__ void cvt_bf16(const float* __restrict__ in, u16* __restrict__ out, int n4) {
  int i = blockIdx.x * blockDim.x + threadIdx.x;
  if (i >= n4) return;
  const float4 v = ((const float4*)in)[i];
  uint32_t lo = (uint32_t)f2b(v.x) | ((uint32_t)f2b(v.y) << 16);
  uint32_t hi = (uint32_t)f2b(v.z) | ((uint32_t)f2b(v.w) << 16);
  ((uint2*)out)[i] = make_uint2(lo, hi);
}

// ---------------- generic C = A * B^T  (bf16 in, f32 accum) ----------------
template<int MODE>
__global__ __launch_bounds__(256) void gemm_bt(
    const u16* __restrict__ A, const u16* __restrict__ B,
    float* __restrict__ Cf, u16* __restrict__ Ck, u16* __restrict__ Ckt,
    int M, int N, int Kd) {
  const int bm = blockIdx.x % (M >> 6);
  const int bn = blockIdx.x / (M >> 6);
  const int w = threadIdx.x >> 6, l = threadIdx.x & 63;
  const int lg = l >> 4, lm = l & 15;
  const int m0 = (bm << 6) + (w << 4);
  const int n0 = bn << 6;

  const u16* Ar = A + (size_t)(m0 + lm) * Kd;
  f32x4 acc[4] = {};

  for (int kd = 0; kd < Kd; kd += 64) {
    short8 a0 = *(const short8*)(Ar + kd + lg * 8);
    short8 a1 = *(const short8*)(Ar + kd + 32 + lg * 8);
#pragma unroll
    for (int nf = 0; nf < 4; ++nf) {
      const u16* Br = B + (size_t)(n0 + nf * 16 + lm) * Kd + kd + lg * 8;
      short8 b0 = *(const short8*)(Br);
      short8 b1 = *(const short8*)(Br + 32);
      acc[nf] = __builtin_amdgcn_mfma_f32_16x16x32_bf16(a0, b0, acc[nf], 0, 0, 0);
      acc[nf] = __builtin_amdgcn_mfma_f32_16x16x32_bf16(a1, b1, acc[nf], 0, 0, 0);
    }
  }

  if (MODE == 0) {
#pragma unroll
    for (int nf = 0; nf < 4; ++nf)
#pragma unroll
      for (int r = 0; r < 4; ++r)
        Cf[(size_t)(m0 + lg * 4 + r) * N + (n0 + nf * 16 + lm)] = acc[nf][r];
  } else {
#pragma unroll
    for (int nf = 0; nf < 4; ++nf) {
      int n = n0 + nf * 16 + lm;
      int h = n >> 6, z = n & 63;
#pragma unroll
      for (int r = 0; r < 4; ++r) {
        int k = m0 + lg * 4 + r;
        u16 b = f2b(acc[nf][r]);
        Ck[((size_t)h * NCTX + k) * HD + z] = b;
        Ckt[((size_t)h * HD + z) * NCTX + k] = b;
      }
    }
  }
}

// ---------------- 5-step energy attention, K-split across 4 waves ----------------
// grid: 2048 blocks = 16 heads x 128 q-tiles of 16 rows. 256 threads (4 waves).
// Wave w owns K slice [w*1024, w*1024+1024). Wave 0 is master: holds q (f32),
// merges per-wave (l, O) partials each step, restages q to shared LDS.
// No max-tracking softmax: beta*score*log2e bounded by ~7 -> exp2 safe in f32.
__global__ __launch_bounds__(256) void attn5(
    const u16* __restrict__ Kbf,   // [NH][NCTX][HD]
    const u16* __restrict__ Ktb,   // [NH][HD][NCTX]
    const float* __restrict__ Qf,  // [NTGT][DMODEL]
    u16* __restrict__ Qob) {       // [NTGT][DMODEL] bf16
  // layout: [0,16384): per-wave 4KB region (P-stage u16[1024] aliased with
  //   O-partial f32[16][64]); [16384,18432): shared q bf16[16][64] swizzled;
  //   [18432,18688): l partials f32[4][16].
  __shared__ __align__(16) uint8_t smem[18688];

  const int bid = blockIdx.x;
  const int h  = ((bid & 7) << 1) | ((bid >> 3) & 1);  // 2 heads per XCD
  const int qt = bid >> 4;
  const int w = threadIdx.x >> 6, l = threadIdx.x & 63;
  const int lg = l >> 4, lm = l & 15;
  const int q0 = qt * 16;

  const u16* Kh  = Kbf + (size_t)h * NCTX * HD;
  const u16* Kth = Ktb + (size_t)h * HD * NCTX;
  u16*   myP = (u16*)(smem + w * 4096);
  u16*   sQ  = (u16*)(smem + 16384);
  float* sL  = (float*)(smem + 18432);

  const float BL2E = 0.125f * 1.44269504088896340736f;  // beta * log2(e)
  const int kbeg = w << 10;
  const int kend = kbeg + 1024;

  float qv[4][4];
  if (w == 0) {
#pragma unroll
    for (int nf = 0; nf < 4; ++nf)
#pragma unroll
      for (int r = 0; r < 4; ++r)
        qv[nf][r] = Qf[(size_t)(q0 + lg * 4 + r) * DMODEL + h * HD + nf * 16 + lm];
    // stage q -> sQ (bf16, XOR-swizzled)
#pragma unroll
    for (int nf = 0; nf < 4; ++nf)
#pragma unroll
      for (int r = 0; r < 4; ++r) {
        int row = lg * 4 + r;
        sQ[(row << 6) + ((nf * 16 + lm) ^ ((row & 7) << 3))] = f2b(qv[nf][r]);
      }
  }

  for (int step = 0; step < 5; ++step) {
    __syncthreads();  // B1: sQ ready
    short8 qa0 = *(const short8*)&sQ[(lm << 6) + ((lg * 8) ^ ((lm & 7) << 3))];
    short8 qa1 = *(const short8*)&sQ[(lm << 6) + ((32 + lg * 8) ^ ((lm & 7) << 3))];

    float lrow[4] = {0.f, 0.f, 0.f, 0.f};
    f32x4 ov[4] = {};

    for (int k0 = kbeg; k0 < kend; k0 += 64) {
      // ---- S = q K^T for this 16x64 tile ----
      f32x4 s[4] = {};
#pragma unroll
      for (int nf = 0; nf < 4; ++nf) {
        const u16* kp = Kh + (size_t)(k0 + nf * 16 + lm) * HD + lg * 8;
        short8 b0 = *(const short8*)kp;
        short8 b1 = *(const short8*)(kp + 32);
        s[nf] = __builtin_amdgcn_mfma_f32_16x16x32_bf16(qa0, b0, s[nf], 0, 0, 0);
        s[nf] = __builtin_amdgcn_mfma_f32_16x16x32_bf16(qa1, b1, s[nf], 0, 0, 0);
      }
      // ---- P = exp2(S * beta*log2e), no max subtraction; defer row-sum ----
      float p[4][4];
#pragma unroll
      for (int nf = 0; nf < 4; ++nf)
#pragma unroll
        for (int r = 0; r < 4; ++r) {
          float pv = exp2f(s[nf][r] * BL2E);
          p[nf][r] = pv;
          lrow[r] += pv;
        }
      // ---- stage P (bf16, swizzled) and O += P * K ----
#pragma unroll
      for (int nf = 0; nf < 4; ++nf)
#pragma unroll
        for (int r = 0; r < 4; ++r) {
          int row = lg * 4 + r;
          myP[(row << 6) + ((nf * 16 + lm) ^ ((row & 7) << 3))] = f2b(p[nf][r]);
        }
      short8 pa0 = *(const short8*)&myP[(lm << 6) + ((lg * 8) ^ ((lm & 7) << 3))];
      short8 pa1 = *(const short8*)&myP[(lm << 6) + ((32 + lg * 8) ^ ((lm & 7) << 3))];
#pragma unroll
      for (int nf = 0; nf < 4; ++nf) {
        const u16* ktp = Kth + (size_t)(nf * 16 + lm) * NCTX + k0 + lg * 8;
        short8 c0 = *(const short8*)ktp;
        short8 c1 = *(const short8*)(ktp + 32);
        ov[nf] = __builtin_amdgcn_mfma_f32_16x16x32_bf16(pa0, c0, ov[nf], 0, 0, 0);
        ov[nf] = __builtin_amdgcn_mfma_f32_16x16x32_bf16(pa1, c1, ov[nf], 0, 0, 0);
      }
    }

    // deferred row-sum across the 16 lanes of each lg-group
#pragma unroll
    for (int r = 0; r < 4; ++r) {
      float ps = lrow[r];
      ps += __shfl_xor(ps, 1);
      ps += __shfl_xor(ps, 2);
      ps += __shfl_xor(ps, 4);
      ps += __shfl_xor(ps, 8);
      lrow[r] = ps;
    }

    if (w != 0) {
      float* myO = (float*)(smem + w * 4096);  // aliases myP (done with it)
#pragma unroll
      for (int nf = 0; nf < 4; ++nf)
#pragma unroll
        for (int r = 0; r < 4; ++r)
          myO[((lg * 4 + r) << 6) + nf * 16 + lm] = ov[nf][r];
      if (lm == 0) {
#pragma unroll
        for (int r = 0; r < 4; ++r) sL[w * 16 + lg * 4 + r] = lrow[r];
      }
    }
    __syncthreads();  // B2: partials ready

    if (w == 0) {
      float lt[4];
#pragma unroll
      for (int r = 0; r < 4; ++r) {
        int row = lg * 4 + r;
        lt[r] = lrow[r] + sL[16 + row] + sL[32 + row] + sL[48 + row];
      }
#pragma unroll
      for (int nf = 0; nf < 4; ++nf)
#pragma unroll
        for (int r = 0; r < 4; ++r) {
          int idx = ((lg * 4 + r) << 6) + nf * 16 + lm;
          float o = ov[nf][r]
                  + ((const float*)(smem + 4096))[idx]
                  + ((const float*)(smem + 8192))[idx]
                  + ((const float*)(smem + 12288))[idx];
          qv[nf][r] += o * (0.1f / lt[r]);
        }
      if (step < 4) {
#pragma unroll
        for (int nf = 0; nf < 4; ++nf)
#pragma unroll
          for (int r = 0; r < 4; ++r) {
            int row = lg * 4 + r;
            sQ[(row << 6) + ((nf * 16 + lm) ^ ((row & 7) << 3))] = f2b(qv[nf][r]);
          }
      }
    }
  }

  if (w == 0) {
#pragma unroll
    for (int nf = 0; nf < 4; ++nf)
#pragma unroll
      for (int r = 0; r < 4; ++r)
        Qob[(size_t)(q0 + lg * 4 + r) * DMODEL + h * HD + nf * 16 + lm] = f2b(qv[nf][r]);
  }
}

extern "C" void kernel_launch(void* const* d_in, const int* in_sizes, int n_in,
                              void* d_out, int out_size, void* d_ws, size_t ws_size,
                              hipStream_t stream) {
  const float* ctx = (const float*)d_in[0];
  const float* tgt = (const float*)d_in[1];
  const float* Wq  = (const float*)d_in[2];
  const float* Wk  = (const float*)d_in[3];
  const float* Wo  = (const float*)d_in[4];

  uint8_t* wp = (uint8_t*)d_ws;
  u16* ctxb = (u16*)wp; wp += (size_t)NCTX * DMODEL * 2;
  u16* tgtb = (u16*)wp; wp += (size_t)NTGT * DMODEL * 2;
  u16* wqb  = (u16*)wp; wp += (size_t)DMODEL * DMODEL * 2;
  u16* wkb  = (u16*)wp; wp += (size_t)DMODEL * DMODEL * 2;
  u16* wob  = (u16*)wp; wp += (size_t)DMODEL * DMODEL * 2;
  u16* Kbf  = (u16*)wp; wp += (size_t)NH * NCTX * HD * 2;
  u16* Ktb  = (u16*)wp; wp += (size_t)NH * HD * NCTX * 2;
  float* Qf = (float*)wp; wp += (size_t)NTGT * DMODEL * 4;
  u16* Qob  = (u16*)wp; wp += (size_t)NTGT * DMODEL * 2;

  auto cvt = [&](const float* in, u16* out, size_t n) {
    int n4 = (int)(n / 4);
    hipLaunchKernelGGL(cvt_bf16, dim3((n4 + 255) / 256), dim3(256), 0, stream, in, out, n4);
  };
  cvt(ctx, ctxb, (size_t)NCTX * DMODEL);
  cvt(tgt, tgtb, (size_t)NTGT * DMODEL);
  cvt(Wq, wqb, (size_t)DMODEL * DMODEL);
  cvt(Wk, wkb, (size_t)DMODEL * DMODEL);
  cvt(Wo, wob, (size_t)DMODEL * DMODEL);

  hipLaunchKernelGGL(gemm_bt<1>, dim3((NCTX / 64) * (DMODEL / 64)), dim3(256), 0, stream,
                     ctxb, wkb, (float*)nullptr, Kbf, Ktb, NCTX, DMODEL, DMODEL);
  hipLaunchKernelGGL(gemm_bt<0>, dim3((NTGT / 64) * (DMODEL / 64)), dim3(256), 0, stream,
                     tgtb, wqb, Qf, (u16*)nullptr, (u16*)nullptr, NTGT, DMODEL, DMODEL);
  hipLaunchKernelGGL(attn5, dim3(2048), dim3(256), 0, stream, Kbf, Ktb, Qf, Qob);
  hipLaunchKernelGGL(gemm_bt<0>, dim3((NTGT / 64) * (DMODEL / 64)), dim3(256), 0, stream,
                     Qob, wob, (float*)d_out, (u16*)nullptr, (u16*)nullptr, NTGT, DMODEL, DMODEL);
}

// Round 3
// 546.977 us; speedup vs baseline: 2.3834x; 2.3547x over previous
//
#include <hip/hip_runtime.h>
#include <stdint.h>

typedef unsigned short u16;
typedef __attribute__((ext_vector_type(8))) short short8;
typedef __attribute__((ext_vector_type(4))) float f32x4;

#define NCTX 4096
#define NTGT 2048
#define DMODEL 1024
#define NH 16
#define HD 64

typedef const __attribute__((address_space(1))) uint32_t g_u32;
typedef __attribute__((address_space(3))) uint32_t lds_u32;

__device__ inline u16 f2b(float f) {
  unsigned r;
  asm("v_cvt_pk_bf16_f32 %0, %1, %1" : "=v"(r) : "v"(f));
  return (u16)r;
}

// ---------------- f32 -> bf16 conversion ----------------
__global__ void cvt_bf16(const float* __restrict__ in, u16* __restrict__ out, int n4) {
  int i = blockIdx.x * blockDim.x + threadIdx.x;
  if (i >= n4) return;
  const float4 v = ((const float4*)in)[i];
  uint32_t lo = (uint32_t)f2b(v.x) | ((uint32_t)f2b(v.y) << 16);
  uint32_t hi = (uint32_t)f2b(v.z) | ((uint32_t)f2b(v.w) << 16);
  ((uint2*)out)[i] = make_uint2(lo, hi);
}

// ---------------- generic C = A * B^T  (bf16 in, f32 accum) ----------------
template<int MODE>
__global__ __launch_bounds__(256) void gemm_bt(
    const u16* __restrict__ A, const u16* __restrict__ B,
    float* __restrict__ Cf, u16* __restrict__ Ck, u16* __restrict__ Ckt,
    int M, int N, int Kd) {
  const int bm = blockIdx.x % (M >> 6);
  const int bn = blockIdx.x / (M >> 6);
  const int w = threadIdx.x >> 6, l = threadIdx.x & 63;
  const int lg = l >> 4, lm = l & 15;
  const int m0 = (bm << 6) + (w << 4);
  const int n0 = bn << 6;

  const u16* Ar = A + (size_t)(m0 + lm) * Kd;
  f32x4 acc[4] = {};

  for (int kd = 0; kd < Kd; kd += 64) {
    short8 a0 = *(const short8*)(Ar + kd + lg * 8);
    short8 a1 = *(const short8*)(Ar + kd + 32 + lg * 8);
#pragma unroll
    for (int nf = 0; nf < 4; ++nf) {
      const u16* Br = B + (size_t)(n0 + nf * 16 + lm) * Kd + kd + lg * 8;
      short8 b0 = *(const short8*)(Br);
      short8 b1 = *(const short8*)(Br + 32);
      acc[nf] = __builtin_amdgcn_mfma_f32_16x16x32_bf16(a0, b0, acc[nf], 0, 0, 0);
      acc[nf] = __builtin_amdgcn_mfma_f32_16x16x32_bf16(a1, b1, acc[nf], 0, 0, 0);
    }
  }

  if (MODE == 0) {
#pragma unroll
    for (int nf = 0; nf < 4; ++nf)
#pragma unroll
      for (int r = 0; r < 4; ++r)
        Cf[(size_t)(m0 + lg * 4 + r) * N + (n0 + nf * 16 + lm)] = acc[nf][r];
  } else {
#pragma unroll
    for (int nf = 0; nf < 4; ++nf) {
      int n = n0 + nf * 16 + lm;
      int h = n >> 6, z = n & 63;
#pragma unroll
      for (int r = 0; r < 4; ++r) {
        int k = m0 + lg * 4 + r;
        u16 b = f2b(acc[nf][r]);
        Ck[((size_t)h * NCTX + k) * HD + z] = b;
        Ckt[((size_t)h * HD + z) * NCTX + k] = b;
      }
    }
  }
}

// ---------------- 5-step energy attention, shared-LDS staged ----------------
// grid: 512 blocks = 16 heads x 32 q-tiles of 64 rows. 4 waves x 16 rows.
// All waves march the full K together; K-tile + Kt-tile double-buffered in LDS
// via global_load_lds (linear dest, inverse-swizzled source, swizzled reads).
__global__ __launch_bounds__(256, 2) void attn5(
    const u16* __restrict__ Kbf,   // [NH][NCTX][HD]
    const u16* __restrict__ Ktb,   // [NH][HD][NCTX]
    const float* __restrict__ Qf,  // [NTGT][DMODEL]
    u16* __restrict__ Qob) {       // [NTGT][DMODEL] bf16
  __shared__ u16 sK[2][4096];    // [64 k-rows][64 z], 16B-block col ^ (row&7)
  __shared__ u16 sKt[2][4096];   // [64 z-rows][64 k], same swizzle
  __shared__ u16 sP[4][1024];    // per-wave P / q staging, u16-swizzle (row&7)<<3

  const int bid = blockIdx.x;
  const int h  = ((bid & 7) << 1) | ((bid >> 3) & 1);
  const int qt = bid >> 4;
  const int w = threadIdx.x >> 6, l = threadIdx.x & 63;
  const int lg = l >> 4, lm = l & 15;
  const int q0 = qt * 64 + w * 16;

  const u16* Kh  = Kbf + (size_t)h * NCTX * HD;
  const u16* Kth = Ktb + (size_t)h * HD * NCTX;
  u16* myP = sP[w];

  // staging per-lane source addressing: row-in-8 = l>>3, 16B block = (l&7)^(l>>3)
  const int rowoff = l >> 3;
  const int blkoff = ((l & 7) ^ rowoff) << 3;   // element offset within a 64-elem row
  const u16* srcK0  = Kh  + (w * 16 + rowoff) * HD + blkoff;
  const u16* srcKt0 = Kth + (size_t)(w * 16 + rowoff) * NCTX + blkoff;

  const float BL2E = 0.125f * 1.44269504088896340736f;  // beta * log2(e)

  auto STAGE = [&](int buf, int kt) {
    const u16* gk = srcK0 + kt * (64 * HD);
    const u16* gt = srcKt0 + kt * 64;
    __builtin_amdgcn_global_load_lds((g_u32*)gk,            (lds_u32*)&sK[buf][(w * 16) * 64],      16, 0, 0);
    __builtin_amdgcn_global_load_lds((g_u32*)(gk + 8 * HD), (lds_u32*)&sK[buf][(w * 16 + 8) * 64],  16, 0, 0);
    __builtin_amdgcn_global_load_lds((g_u32*)gt,            (lds_u32*)&sKt[buf][(w * 16) * 64],     16, 0, 0);
    __builtin_amdgcn_global_load_lds((g_u32*)(gt + (size_t)8 * NCTX), (lds_u32*)&sKt[buf][(w * 16 + 8) * 64], 16, 0, 0);
  };

  // q in f32 registers, MFMA C-layout
  float qv[4][4];
#pragma unroll
  for (int nf = 0; nf < 4; ++nf)
#pragma unroll
    for (int r = 0; r < 4; ++r)
      qv[nf][r] = Qf[(size_t)(q0 + lg * 4 + r) * DMODEL + h * HD + nf * 16 + lm];

  for (int step = 0; step < 5; ++step) {
    // stage q -> myP (bf16, swizzled), pull A-fragments
#pragma unroll
    for (int nf = 0; nf < 4; ++nf)
#pragma unroll
      for (int r = 0; r < 4; ++r) {
        int row = lg * 4 + r;
        myP[(row << 6) + ((nf * 16 + lm) ^ ((row & 7) << 3))] = f2b(qv[nf][r]);
      }
    short8 qa0 = *(const short8*)&myP[(lm << 6) + ((lg * 8) ^ ((lm & 7) << 3))];
    short8 qa1 = *(const short8*)&myP[(lm << 6) + ((32 + lg * 8) ^ ((lm & 7) << 3))];

    float lrow[4] = {0.f, 0.f, 0.f, 0.f};
    f32x4 ov[4] = {};

    STAGE(0, 0);
    __syncthreads();

#pragma unroll 2
    for (int t = 0; t < NCTX / 64; ++t) {
      const int cur = t & 1;
      if (t < NCTX / 64 - 1) STAGE(cur ^ 1, t + 1);

      // ---- S = q K^T (B-frags from swizzled sK) ----
      f32x4 s[4];
#pragma unroll
      for (int nf = 0; nf < 4; ++nf) {
        short8 b0 = *(const short8*)&sK[cur][nf * 1024 + lm * 64 + ((lg ^ (lm & 7)) << 3)];
        short8 b1 = *(const short8*)&sK[cur][nf * 1024 + lm * 64 + (((lg + 4) ^ (lm & 7)) << 3)];
        f32x4 z = {};
        z = __builtin_amdgcn_mfma_f32_16x16x32_bf16(qa0, b0, z, 0, 0, 0);
        s[nf] = __builtin_amdgcn_mfma_f32_16x16x32_bf16(qa1, b1, z, 0, 0, 0);
      }

      // ---- P = exp2(S*beta*log2e); deferred row-sum ----
      float p[4][4];
#pragma unroll
      for (int nf = 0; nf < 4; ++nf)
#pragma unroll
        for (int r = 0; r < 4; ++r) {
          float pv = exp2f(s[nf][r] * BL2E);
          p[nf][r] = pv;
          lrow[r] += pv;
        }

      // ---- stage P (bf16, swizzled) ----
#pragma unroll
      for (int nf = 0; nf < 4; ++nf)
#pragma unroll
        for (int r = 0; r < 4; ++r) {
          int row = lg * 4 + r;
          myP[(row << 6) + ((nf * 16 + lm) ^ ((row & 7) << 3))] = f2b(p[nf][r]);
        }
      short8 pa0 = *(const short8*)&myP[(lm << 6) + ((lg * 8) ^ ((lm & 7) << 3))];
      short8 pa1 = *(const short8*)&myP[(lm << 6) + ((32 + lg * 8) ^ ((lm & 7) << 3))];

      // ---- O += P * K  (B-frags from swizzled sKt) ----
#pragma unroll
      for (int nf = 0; nf < 4; ++nf) {
        short8 c0 = *(const short8*)&sKt[cur][nf * 1024 + lm * 64 + ((lg ^ (lm & 7)) << 3)];
        short8 c1 = *(const short8*)&sKt[cur][nf * 1024 + lm * 64 + (((lg + 4) ^ (lm & 7)) << 3)];
        ov[nf] = __builtin_amdgcn_mfma_f32_16x16x32_bf16(pa0, c0, ov[nf], 0, 0, 0);
        ov[nf] = __builtin_amdgcn_mfma_f32_16x16x32_bf16(pa1, c1, ov[nf], 0, 0, 0);
      }
      __syncthreads();
    }

    // deferred row-sum across the 16 lanes of each lg-group
#pragma unroll
    for (int r = 0; r < 4; ++r) {
      float ps = lrow[r];
      ps += __shfl_xor(ps, 1);
      ps += __shfl_xor(ps, 2);
      ps += __shfl_xor(ps, 4);
      ps += __shfl_xor(ps, 8);
      float rl = 0.1f / ps;
#pragma unroll
      for (int nf = 0; nf < 4; ++nf) qv[nf][r] += ov[nf][r] * rl;
    }
  }

#pragma unroll
  for (int nf = 0; nf < 4; ++nf)
#pragma unroll
    for (int r = 0; r < 4; ++r)
      Qob[(size_t)(q0 + lg * 4 + r) * DMODEL + h * HD + nf * 16 + lm] = f2b(qv[nf][r]);
}

extern "C" void kernel_launch(void* const* d_in, const int* in_sizes, int n_in,
                              void* d_out, int out_size, void* d_ws, size_t ws_size,
                              hipStream_t stream) {
  const float* ctx = (const float*)d_in[0];
  const float* tgt = (const float*)d_in[1];
  const float* Wq  = (const float*)d_in[2];
  const float* Wk  = (const float*)d_in[3];
  const float* Wo  = (const float*)d_in[4];

  uint8_t* wp = (uint8_t*)d_ws;
  u16* ctxb = (u16*)wp; wp += (size_t)NCTX * DMODEL * 2;
  u16* tgtb = (u16*)wp; wp += (size_t)NTGT * DMODEL * 2;
  u16* wqb  = (u16*)wp; wp += (size_t)DMODEL * DMODEL * 2;
  u16* wkb  = (u16*)wp; wp += (size_t)DMODEL * DMODEL * 2;
  u16* wob  = (u16*)wp; wp += (size_t)DMODEL * DMODEL * 2;
  u16* Kbf  = (u16*)wp; wp += (size_t)NH * NCTX * HD * 2;
  u16* Ktb  = (u16*)wp; wp += (size_t)NH * HD * NCTX * 2;
  float* Qf = (float*)wp; wp += (size_t)NTGT * DMODEL * 4;
  u16* Qob  = (u16*)wp; wp += (size_t)NTGT * DMODEL * 2;

  auto cvt = [&](const float* in, u16* out, size_t n) {
    int n4 = (int)(n / 4);
    hipLaunchKernelGGL(cvt_bf16, dim3((n4 + 255) / 256), dim3(256), 0, stream, in, out, n4);
  };
  cvt(ctx, ctxb, (size_t)NCTX * DMODEL);
  cvt(tgt, tgtb, (size_t)NTGT * DMODEL);
  cvt(Wq, wqb, (size_t)DMODEL * DMODEL);
  cvt(Wk, wkb, (size_t)DMODEL * DMODEL);
  cvt(Wo, wob, (size_t)DMODEL * DMODEL);

  hipLaunchKernelGGL(gemm_bt<1>, dim3((NCTX / 64) * (DMODEL / 64)), dim3(256), 0, stream,
                     ctxb, wkb, (float*)nullptr, Kbf, Ktb, NCTX, DMODEL, DMODEL);
  hipLaunchKernelGGL(gemm_bt<0>, dim3((NTGT / 64) * (DMODEL / 64)), dim3(256), 0, stream,
                     tgtb, wqb, Qf, (u16*)nullptr, (u16*)nullptr, NTGT, DMODEL, DMODEL);
  hipLaunchKernelGGL(attn5, dim3(512), dim3(256), 0, stream, Kbf, Ktb, Qf, Qob);
  hipLaunchKernelGGL(gemm_bt<0>, dim3((NTGT / 64) * (DMODEL / 64)), dim3(256), 0, stream,
                     Qob, wob, (float*)d_out, (u16*)nullptr, (u16*)nullptr, NTGT, DMODEL, DMODEL);
}

// Round 4
// 450.680 us; speedup vs baseline: 2.8927x; 1.2137x over previous
//
#include <hip/hip_runtime.h>
#include <stdint.h>

typedef unsigned short u16;
typedef __attribute__((ext_vector_type(8))) short short8;
typedef __attribute__((ext_vector_type(4))) float f32x4;
typedef __attribute__((ext_vector_type(16))) float f32x16;

#define NCTX 4096
#define NTGT 2048
#define DMODEL 1024
#define NH 16
#define HD 64

typedef const __attribute__((address_space(1))) uint32_t g_u32;
typedef __attribute__((address_space(3))) uint32_t lds_u32;

__device__ inline u16 f2b(float f) {
  unsigned r;
  asm("v_cvt_pk_bf16_f32 %0, %1, %1" : "=v"(r) : "v"(f));
  return (u16)r;
}
__device__ inline uint32_t pk2(float lo, float hi_) {
  uint32_t r;
  asm("v_cvt_pk_bf16_f32 %0, %1, %2" : "=v"(r) : "v"(lo), "v"(hi_));
  return r;
}

// ---------------- f32 -> bf16 conversion ----------------
__global__ void cvt_bf16(const float* __restrict__ in, u16* __restrict__ out, int n4) {
  int i = blockIdx.x * blockDim.x + threadIdx.x;
  if (i >= n4) return;
  const float4 v = ((const float4*)in)[i];
  ((uint2*)out)[i] = make_uint2(pk2(v.x, v.y), pk2(v.z, v.w));
}

// ---------------- generic C = A * B^T  (bf16 in, f32 accum) ----------------
template<int MODE>
__global__ __launch_bounds__(256) void gemm_bt(
    const u16* __restrict__ A, const u16* __restrict__ B,
    float* __restrict__ Cf, u16* __restrict__ Ck, u16* __restrict__ Ckt,
    int M, int N, int Kd) {
  const int bm = blockIdx.x % (M >> 6);
  const int bn = blockIdx.x / (M >> 6);
  const int w = threadIdx.x >> 6, l = threadIdx.x & 63;
  const int lg = l >> 4, lm = l & 15;
  const int m0 = (bm << 6) + (w << 4);
  const int n0 = bn << 6;

  const u16* Ar = A + (size_t)(m0 + lm) * Kd;
  f32x4 acc[4] = {};

  for (int kd = 0; kd < Kd; kd += 64) {
    short8 a0 = *(const short8*)(Ar + kd + lg * 8);
    short8 a1 = *(const short8*)(Ar + kd + 32 + lg * 8);
#pragma unroll
    for (int nf = 0; nf < 4; ++nf) {
      const u16* Br = B + (size_t)(n0 + nf * 16 + lm) * Kd + kd + lg * 8;
      short8 b0 = *(const short8*)(Br);
      short8 b1 = *(const short8*)(Br + 32);
      acc[nf] = __builtin_amdgcn_mfma_f32_16x16x32_bf16(a0, b0, acc[nf], 0, 0, 0);
      acc[nf] = __builtin_amdgcn_mfma_f32_16x16x32_bf16(a1, b1, acc[nf], 0, 0, 0);
    }
  }

  if (MODE == 0) {
#pragma unroll
    for (int nf = 0; nf < 4; ++nf)
#pragma unroll
      for (int r = 0; r < 4; ++r)
        Cf[(size_t)(m0 + lg * 4 + r) * N + (n0 + nf * 16 + lm)] = acc[nf][r];
  } else {
#pragma unroll
    for (int nf = 0; nf < 4; ++nf) {
      int n = n0 + nf * 16 + lm;
      int h = n >> 6, z = n & 63;
#pragma unroll
      for (int r = 0; r < 4; ++r) {
        int k = m0 + lg * 4 + r;
        u16 b = f2b(acc[nf][r]);
        Ck[((size_t)h * NCTX + k) * HD + z] = b;
        Ckt[((size_t)h * HD + z) * NCTX + k] = b;
      }
    }
  }
}

// ---------------- 5-step energy attention, swapped 32x32 MFMA ----------------
// grid: 512 blocks = 16 heads x 32 q-tiles of 64 rows. 4 waves:
//   wave w: q-group qg=w&1 (32 rows), k-half ks=w>>1 (2048 k).
// St = mfma32x32(K, Q) -> P lane-local (q = lane&31); P -> PV A-frag via
// cvt_pk + permlane32_swap (no LDS P round-trip). K/Kt tiles staged with
// global_load_lds, both-sides XOR swizzle. Per-step O/l merge via LDS.
__global__ __launch_bounds__(256, 2) void attn5(
    const u16* __restrict__ Kbf,   // [NH][NCTX][HD]
    const u16* __restrict__ Ktb,   // [NH][HD][NCTX]
    const float* __restrict__ Qf,  // [NTGT][DMODEL]
    u16* __restrict__ Qob) {       // [NTGT][DMODEL] bf16
  __shared__ u16 sT[2][2][4096];     // [kstream][buf][ K 32x64 | Kt 64x32 ]
  __shared__ u16 qscr[2][2048];      // [qg] 32x64 bf16, swizzled
  __shared__ float4 mdump[2][8][64]; // [qg][reg-quad][lane] O partial dump
  __shared__ float lbuf[2][32];
  __shared__ float lfin[2][32];

  const int bid = blockIdx.x;
  const int h  = ((bid & 7) << 1) | ((bid >> 3) & 1);
  const int qt = bid >> 4;
  const int w = threadIdx.x >> 6, l = threadIdx.x & 63;
  const int ln = l & 31, hi = l >> 5;
  const int qg = w & 1, ks = w >> 1;
  const int q0 = qt * 64 + qg * 32;
  const int kbase = ks * 2048;

  const u16* Kh  = Kbf + (size_t)h * NCTX * HD;
  const u16* Kth = Ktb + (size_t)h * HD * NCTX;
  u16* sbase = &sT[ks][0][0];

  const float BL2E = 0.125f * 1.44269504088896340736f;  // beta * log2(e)

  // ---- Q B-frags: lane q=ln, z = zc*16 + 8*hi + e ----
  short8 qfrag[4];
  {
    const float* qp = Qf + (size_t)(q0 + ln) * DMODEL + h * HD + hi * 8;
#pragma unroll
    for (int zc = 0; zc < 4; ++zc) {
      float4 f0 = *(const float4*)(qp + zc * 16);
      float4 f1 = *(const float4*)(qp + zc * 16 + 4);
      union { short8 s; uint32_t u[4]; } t;
      t.u[0] = pk2(f0.x, f0.y); t.u[1] = pk2(f0.z, f0.w);
      t.u[2] = pk2(f1.x, f1.y); t.u[3] = pk2(f1.z, f1.w);
      qfrag[zc] = t.s;
    }
  }
  // ---- q state in C-layout (only k-half-0 waves maintain it) ----
  float qreg[2][16];
  if (ks == 0) {
#pragma unroll
    for (int zb = 0; zb < 2; ++zb)
#pragma unroll
      for (int rr = 0; rr < 16; ++rr) {
        int qq = (rr & 3) + 8 * (rr >> 2) + 4 * hi;
        qreg[zb][rr] = Qf[(size_t)(q0 + qq) * DMODEL + h * HD + zb * 32 + ln];
      }
  }

  auto STAGE = [&](int buf, int t) {
    const int k0 = kbase + t * 32;
    if (qg == 0) {  // K part [32 k][64 z], block-col ^= (row&7)
      const u16* src = Kh + (size_t)(k0 + (l >> 3)) * HD + (((l & 7) ^ ((l >> 3) & 7)) << 3);
#pragma unroll
      for (int i = 0; i < 4; ++i)
        __builtin_amdgcn_global_load_lds((g_u32*)(src + i * 8 * HD),
            (lds_u32*)(sbase + buf * 4096 + i * 512), 16, 0, 0);
    } else {        // Kt part [64 z][32 k], block-col ^= ((z>>1)&3)
      const u16* src = Kth + (size_t)(l >> 2) * NCTX + k0 + (((l & 3) ^ ((l >> 3) & 3)) << 3);
#pragma unroll
      for (int i = 0; i < 4; ++i)
        __builtin_amdgcn_global_load_lds((g_u32*)(src + (size_t)i * 16 * NCTX),
            (lds_u32*)(sbase + buf * 4096 + 2048 + i * 512), 16, 0, 0);
    }
  };

  for (int step = 0; step < 5; ++step) {
    f32x16 acc0 = {}, acc1 = {};
    float lrow = 0.f;

    STAGE(0, 0);
    __syncthreads();

#pragma unroll 2
    for (int t = 0; t < 64; ++t) {
      const int buf = t & 1;
      if (t < 63) STAGE(buf ^ 1, t + 1);
      const u16* tb = sbase + buf * 4096;

      // ---- St[k][q] = sum_z K[k][z] Q[q][z] ----
      f32x16 st = {};
#pragma unroll
      for (int zc = 0; zc < 4; ++zc) {
        short8 kf = *(const short8*)(tb + ln * 64 + (((zc * 2 + hi) ^ (ln & 7)) << 3));
        st = __builtin_amdgcn_mfma_f32_32x32x16_bf16(kf, qfrag[zc], st, 0, 0, 0);
      }
      // ---- P = exp2(St * c); lane-local row-sum ----
      float p[16];
#pragma unroll
      for (int j = 0; j < 16; ++j) {
        p[j] = exp2f(st[j] * BL2E);
        lrow += p[j];
      }
      // ---- PA frags via cvt_pk + permlane32_swap; O += P*K ----
#pragma unroll
      for (int kc = 0; kc < 2; ++kc) {
        uint32_t a0 = pk2(p[8 * kc + 0], p[8 * kc + 1]);
        uint32_t a1 = pk2(p[8 * kc + 2], p[8 * kc + 3]);
        uint32_t b0 = pk2(p[8 * kc + 4], p[8 * kc + 5]);
        uint32_t b1 = pk2(p[8 * kc + 6], p[8 * kc + 7]);
        asm("v_permlane32_swap_b32 %0, %1" : "+v"(a0), "+v"(b0));
        asm("v_permlane32_swap_b32 %0, %1" : "+v"(a1), "+v"(b1));
        union { short8 s; uint32_t u[4]; } pa;
        pa.u[0] = a0; pa.u[1] = a1; pa.u[2] = b0; pa.u[3] = b1;
        const u16* kt = tb + 2048;
        int swz = ((kc * 2 + hi) ^ ((ln >> 1) & 3)) << 3;
        short8 v0 = *(const short8*)(kt + ln * 32 + swz);
        short8 v1 = *(const short8*)(kt + (32 + ln) * 32 + swz);
        acc0 = __builtin_amdgcn_mfma_f32_32x32x16_bf16(pa.s, v0, acc0, 0, 0, 0);
        acc1 = __builtin_amdgcn_mfma_f32_32x32x16_bf16(pa.s, v1, acc1, 0, 0, 0);
      }
      __syncthreads();
    }

    lrow += __shfl_xor(lrow, 32);

    // ---- merge k-halves ----
    if (ks == 1) {
#pragma unroll
      for (int jc = 0; jc < 4; ++jc) {
        mdump[qg][jc][l]     = make_float4(acc0[4 * jc], acc0[4 * jc + 1], acc0[4 * jc + 2], acc0[4 * jc + 3]);
        mdump[qg][jc + 4][l] = make_float4(acc1[4 * jc], acc1[4 * jc + 1], acc1[4 * jc + 2], acc1[4 * jc + 3]);
      }
      if (hi == 0) lbuf[qg][ln] = lrow;
    }
    __syncthreads();
    if (ks == 0) {
#pragma unroll
      for (int jc = 0; jc < 4; ++jc) {
        float4 d0 = mdump[qg][jc][l];
        float4 d1 = mdump[qg][jc + 4][l];
        acc0[4 * jc] += d0.x; acc0[4 * jc + 1] += d0.y; acc0[4 * jc + 2] += d0.z; acc0[4 * jc + 3] += d0.w;
        acc1[4 * jc] += d1.x; acc1[4 * jc + 1] += d1.y; acc1[4 * jc + 2] += d1.z; acc1[4 * jc + 3] += d1.w;
      }
      float lt = lrow + lbuf[qg][ln];
      if (hi == 0) lfin[qg][ln] = lt;
      // ---- q update + restage / output ----
#pragma unroll
      for (int rr = 0; rr < 16; ++rr) {
        int qq = (rr & 3) + 8 * (rr >> 2) + 4 * hi;
        float sc = 0.1f / lfin[qg][qq];
        qreg[0][rr] += acc0[rr] * sc;
        qreg[1][rr] += acc1[rr] * sc;
      }
      if (step < 4) {
#pragma unroll
        for (int zb = 0; zb < 2; ++zb)
#pragma unroll
          for (int rr = 0; rr < 16; ++rr) {
            int qq = (rr & 3) + 8 * (rr >> 2) + 4 * hi;
            int z = zb * 32 + ln;
            qscr[qg][qq * 64 + (((z >> 3) ^ (qq & 7)) << 3) + (z & 7)] = f2b(qreg[zb][rr]);
          }
      } else {
#pragma unroll
        for (int zb = 0; zb < 2; ++zb)
#pragma unroll
          for (int rr = 0; rr < 16; ++rr) {
            int qq = (rr & 3) + 8 * (rr >> 2) + 4 * hi;
            Qob[(size_t)(q0 + qq) * DMODEL + h * HD + zb * 32 + ln] = f2b(qreg[zb][rr]);
          }
      }
    }
    __syncthreads();
    if (step < 4) {
#pragma unroll
      for (int zc = 0; zc < 4; ++zc)
        qfrag[zc] = *(const short8*)(&qscr[qg][ln * 64 + (((zc * 2 + hi) ^ (ln & 7)) << 3)]);
    }
  }
}

extern "C" void kernel_launch(void* const* d_in, const int* in_sizes, int n_in,
                              void* d_out, int out_size, void* d_ws, size_t ws_size,
                              hipStream_t stream) {
  const float* ctx = (const float*)d_in[0];
  const float* tgt = (const float*)d_in[1];
  const float* Wq  = (const float*)d_in[2];
  const float* Wk  = (const float*)d_in[3];
  const float* Wo  = (const float*)d_in[4];

  uint8_t* wp = (uint8_t*)d_ws;
  u16* ctxb = (u16*)wp; wp += (size_t)NCTX * DMODEL * 2;
  u16* tgtb = (u16*)wp; wp += (size_t)NTGT * DMODEL * 2;
  u16* wqb  = (u16*)wp; wp += (size_t)DMODEL * DMODEL * 2;
  u16* wkb  = (u16*)wp; wp += (size_t)DMODEL * DMODEL * 2;
  u16* wob  = (u16*)wp; wp += (size_t)DMODEL * DMODEL * 2;
  u16* Kbf  = (u16*)wp; wp += (size_t)NH * NCTX * HD * 2;
  u16* Ktb  = (u16*)wp; wp += (size_t)NH * HD * NCTX * 2;
  float* Qf = (float*)wp; wp += (size_t)NTGT * DMODEL * 4;
  u16* Qob  = (u16*)wp; wp += (size_t)NTGT * DMODEL * 2;

  auto cvt = [&](const float* in, u16* out, size_t n) {
    int n4 = (int)(n / 4);
    hipLaunchKernelGGL(cvt_bf16, dim3((n4 + 255) / 256), dim3(256), 0, stream, in, out, n4);
  };
  cvt(ctx, ctxb, (size_t)NCTX * DMODEL);
  cvt(tgt, tgtb, (size_t)NTGT * DMODEL);
  cvt(Wq, wqb, (size_t)DMODEL * DMODEL);
  cvt(Wk, wkb, (size_t)DMODEL * DMODEL);
  cvt(Wo, wob, (size_t)DMODEL * DMODEL);

  hipLaunchKernelGGL(gemm_bt<1>, dim3((NCTX / 64) * (DMODEL / 64)), dim3(256), 0, stream,
                     ctxb, wkb, (float*)nullptr, Kbf, Ktb, NCTX, DMODEL, DMODEL);
  hipLaunchKernelGGL(gemm_bt<0>, dim3((NTGT / 64) * (DMODEL / 64)), dim3(256), 0, stream,
                     tgtb, wqb, Qf, (u16*)nullptr, (u16*)nullptr, NTGT, DMODEL, DMODEL);
  hipLaunchKernelGGL(attn5, dim3(512), dim3(256), 0, stream, Kbf, Ktb, Qf, Qob);
  hipLaunchKernelGGL(gemm_bt<0>, dim3((NTGT / 64) * (DMODEL / 64)), dim3(256), 0, stream,
                     Qob, wob, (float*)d_out, (u16*)nullptr, (u16*)nullptr, NTGT, DMODEL, DMODEL);
}